// Round 8
// baseline (1412.291 us; speedup 1.0000x reference)
//
#include <hip/hip_runtime.h>
#include <hip/hip_cooperative_groups.h>

namespace cg = cooperative_groups;

#define DEV __device__ __forceinline__

// Problem constants
constexpr int Cc = 64, DIc = 128, Sc = 16, Rc = 4, Kc = 4;
constexpr int Lc = 2304, Tc = 4;
constexpr int NCH = 144, CHL = 16;   // 144 chunks of length 16

// Workspace layout (float offsets). 5 slots: 0-3 = bias branch t=0..3, 4 = s-branch.
constexpr int OFF_XCPRE = 0;              // L*DI  [l][d]
constexpr int OFF_Z     = 294912;         // L*DI  [l][d]
constexpr int OFF_XACT  = 589824;         // L*DI  [l][d]
constexpr int OFF_DTS   = 884736;         // K*R*L [k][r][pos]
constexpr int OFF_BS    = 921600;         // K*L*S [k][pos][s]
constexpr int OFF_CS    = 1069056;        // K*L*S
constexpr int OFF_Y     = 1216512;        // K*L*DI [k][pos][d]
constexpr int OFF_SUMA  = 2396160;        // K*NCH*S*DI  (lane-major in d)
constexpr int OFF_SUMB  = 3575808;
constexpr int OFF_H0    = 4755456;
constexpr int SLOTF     = 5935104;
constexpr int OFF_B0    = 5 * SLOTF;      // L*C state buffers [l][c]
constexpr int OFF_B1    = OFF_B0 + Lc * Cc;
constexpr int OFF_B2    = OFF_B1 + Lc * Cc;
constexpr int OFF_BIAS  = OFF_B2 + Lc * Cc;       // T*L*C [t][l][c]
// Lane-major transposed weights:
constexpr int OFF_TW    = OFF_BIAS + Tc * Lc * Cc;
constexpr int TW_INW  = 0;        // [2][64][256]
constexpr int TW_XPW  = 32768;    // [2][128][144]
constexpr int TW_OW   = 69632;    // [2][128][64]
constexpr int TW_CW   = 86016;    // [2][9][128]
constexpr int TW_AT   = 88320;    // [2][4][16][128]
constexpr int TW_DTW  = 104704;   // [2][4][4][128]

struct Params {
  const float *img, *dz, *sigma, *in_w, *in_b, *conv_w, *conv_b, *xp_w, *dt_w,
              *dt_b, *A_logs, *Ds, *onw, *onb, *ow, *ob, *niw, *nib, *ndw, *ndb;
  float* outp;
  float* ws;
};

DEV float wsum(float v) {
#pragma unroll
  for (int m = 32; m; m >>= 1) v += __shfl_xor(v, m, 64);
  return v;
}
DEV float wmax(float v) {
#pragma unroll
  for (int m = 32; m; m >>= 1) v = fmaxf(v, __shfl_xor(v, m, 64));
  return v;
}
DEV float sigmoidf(float x) { return 1.f / (1.f + __expf(-x)); }
DEV float softplusf(float v) { return (v > 20.f) ? v : __logf(1.f + __expf(v)); }

// scan-position -> row-major pixel index, per direction
DEV int perm_idx(int k, int l) {
  if (k == 0) return l;
  if (k == 1) return (l % 48) * 48 + l / 48;
  if (k == 2) return Lc - 1 - l;
  int pp = Lc - 1 - l;
  return (pp % 48) * 48 + pp / 48;
}

// ---------------------------------------------------------------------------
// phase bodies (block-unit bu = old blockIdx.x [+ slot partition])

DEV void ph_transpose(int bu, int tid, const Params& p, float* tw) {
  int i = bu * 256 + tid;
  if (i < 32768) {  // inwT
    int d = i & 255, cc = (i >> 8) & 63, b = i >> 14;
    tw[TW_INW + i] = p.in_w[(b * 256 + d) * 64 + cc];
  }
  if (i < 36864) {  // xpwT
    int kr = i % 144, cc = (i / 144) & 127, b = i / (144 * 128);
    tw[TW_XPW + i] = p.xp_w[(b * 144 + kr) * 128 + cc];
  }
  if (i < 16384) {  // owT
    int c = i & 63, d = (i >> 6) & 127, b = i >> 13;
    tw[TW_OW + i] = p.ow[(b * 64 + c) * 128 + d];
  }
  if (i < 2304) {   // cwT
    int d = i & 127, kk = (i >> 7) % 9, b = i / 1152;
    tw[TW_CW + i] = p.conv_w[(b * 128 + d) * 9 + kk];
  }
  if (i < 16384) {  // AT
    int d = i & 127, bks = i >> 7;
    int s = bks & 15, bk = bks >> 4;
    tw[TW_AT + i] = p.A_logs[(bk * 128 + d) * 16 + s];
  }
  if (i < 4096) {   // dtwT
    int d = i & 127, bkr = i >> 7;
    int r = bkr & 3, bk = bkr >> 2;
    tw[TW_DTW + i] = p.dt_w[(bk * 128 + d) * 4 + r];
  }
}

DEV void ph_prep(int blk, int tid, const Params& p, float* ws) {
  int wv = tid >> 6, c = tid & 63;
  int l = blk * 4 + wv;
  float v = p.dz[c * Lc + l];
  float mu = wsum(v) * (1.f / 64.f);
  float var = wsum(v * v) * (1.f / 64.f) - mu * mu;
  float pv = (v - mu) * rsqrtf(var + 1e-6f) * p.ndw[c] + p.ndb[c];
  (ws + OFF_B0)[l * Cc + c] = pv;
  (ws + OFF_B1)[l * Cc + c] = pv * __expf(p.sigma[c * Lc + l]);
}

DEV void ph_inproj(int slot, int blk, int tid, const Params& p, float* ws, float* sm) {
  float (*xv)[64] = (float(*)[64])sm;
  int branch = (slot >= 4) ? 0 : 1;
  float* base = ws + (size_t)slot * SLOTF;
  float* xcpre = base + OFF_XCPRE;
  float* zbuf  = base + OFF_Z;
  const float* prevb = ws + OFF_B0;
  const float* curb  = ws + OFF_B1;
  const float* wT = ws + OFF_TW + TW_INW + branch * 64 * 256;
  int l0 = blk * 8;
  int wv = tid >> 6, c = tid & 63;
#pragma unroll
  for (int q = 0; q < 2; q++) {
    int pp = wv * 2 + q;
    int l = l0 + pp;
    float x;
    if (branch == 1) {
      float v = p.img[(slot * Cc + c) * Lc + l];
      float mu = wsum(v) * (1.f / 64.f);
      float var = wsum(v * v) * (1.f / 64.f) - mu * mu;
      x = (v - mu) * rsqrtf(var + 1e-6f) * p.niw[c] + p.nib[c];
    } else {
      float pv = prevb[l * Cc + c], cv = curb[l * Cc + c];
      float mp = wmax(pv);
      float sp = wsum(__expf(pv - mp));
      float lp = pv - mp - __logf(sp);
      float mq = wmax(cv);
      float sq = wsum(__expf(cv - mq));
      float lq = cv - mq - __logf(sq);
      x = __expf(lp) * (lp - lq);
    }
    xv[pp][c] = x;
  }
  __syncthreads();
  int d = tid;
  float acc[8];
#pragma unroll
  for (int q = 0; q < 8; q++) acc[q] = 0.f;
  for (int cc = 0; cc < Cc; cc++) {
    float wval = wT[cc * 256 + d];
#pragma unroll
    for (int q = 0; q < 8; q++) acc[q] += wval * xv[q][cc];
  }
  float bv = p.in_b[branch * 2 * DIc + d];
  if (d < DIc) {
#pragma unroll
    for (int q = 0; q < 8; q++) xcpre[(l0 + q) * DIc + d] = acc[q] + bv;
  } else {
    int dd = d - DIc;
#pragma unroll
    for (int q = 0; q < 8; q++) zbuf[(l0 + q) * DIc + dd] = acc[q] + bv;
  }
}

DEV void ph_conv(int slot, int blk, int tid, const Params& p, float* ws, float* sm) {
  float (*xv)[DIc] = (float(*)[DIc])sm;
  int branch = (slot >= 4) ? 0 : 1;
  float* base = ws + (size_t)slot * SLOTF;
  float* xcpre = base + OFF_XCPRE;
  float* xact  = base + OFF_XACT;
  float* dtsb  = base + OFF_DTS;
  float* Bsb   = base + OFF_BS;
  float* Csb   = base + OFF_CS;
  const float* cwT  = ws + OFF_TW + TW_CW + branch * 9 * 128;
  const float* xpwT = ws + OFF_TW + TW_XPW + branch * 128 * 144;
  int h = blk / 12;
  int w0 = (blk % 12) * 4;
  for (int it = tid; it < 4 * DIc; it += 256) {
    int d = it & (DIc - 1);
    int pp = it >> 7;
    int w = w0 + pp;
    float acc = 0.f;
#pragma unroll
    for (int kh = 0; kh < 3; kh++) {
      int hh = h + kh - 1;
      if ((unsigned)hh < 48u) {
#pragma unroll
        for (int kw = 0; kw < 3; kw++) {
          int wp = w + kw - 1;
          if ((unsigned)wp < 48u)
            acc += cwT[(kh * 3 + kw) * 128 + d] * xcpre[(hh * 48 + wp) * DIc + d];
        }
      }
    }
    float v = acc + p.conv_b[branch * DIc + d];
    float s = v * sigmoidf(v);
    xv[pp][d] = s;
    xact[(h * 48 + w) * DIc + d] = s;
  }
  __syncthreads();
  if (tid < Kc * 36) {
    int k = tid / 36, r = tid % 36;
    float acc[4] = {0.f, 0.f, 0.f, 0.f};
    for (int cc = 0; cc < DIc; cc++) {
      float wvv = xpwT[cc * 144 + tid];
#pragma unroll
      for (int pp = 0; pp < 4; pp++) acc[pp] += wvv * xv[pp][cc];
    }
#pragma unroll
    for (int pp = 0; pp < 4; pp++) {
      int w = w0 + pp;
      int lr = h * 48 + w, lcx = w * 48 + h;
      int pos = (k == 0) ? lr : (k == 1) ? lcx : (k == 2) ? (Lc - 1 - lr) : (Lc - 1 - lcx);
      if (r < Rc) dtsb[(k * Rc + r) * Lc + pos] = acc[pp];
      else if (r < Rc + Sc) Bsb[(k * Lc + pos) * Sc + (r - Rc)] = acc[pp];
      else Csb[(k * Lc + pos) * Sc + (r - Rc - Sc)] = acc[pp];
    }
  }
}

DEV void ph_scan1(int slot, int bu, int tid, const Params& p, float* ws) {
  int gid = bu * 256 + tid;
  int branch = (slot >= 4) ? 0 : 1;
  float* base = ws + (size_t)slot * SLOTF;
  const float* xact = base + OFF_XACT;
  const float* Bsb  = base + OFF_BS;
  const float* dtsb = base + OFF_DTS;
  float* sumA = base + OFF_SUMA;
  float* sumB = base + OFF_SUMB;
  int d = gid & (DIc - 1);
  int k = (gid >> 7) & 3;
  int ch = gid >> 9;
  int bk = branch * Kc + k;
  const float* AT   = ws + OFF_TW + TW_AT;
  const float* dtwT = ws + OFF_TW + TW_DTW;
  float A[Sc];
#pragma unroll
  for (int s = 0; s < Sc; s++) A[s] = -__expf(AT[(bk * 16 + s) * 128 + d]);
  float dw[Rc];
#pragma unroll
  for (int r = 0; r < Rc; r++) dw[r] = dtwT[(bk * 4 + r) * 128 + d];
  float db = p.dt_b[bk * DIc + d];
  float pA[Sc], aB[Sc];
#pragma unroll
  for (int s = 0; s < Sc; s++) { pA[s] = 1.f; aB[s] = 0.f; }
  int l0 = ch * CHL;
  for (int i = 0; i < CHL; i++) {
    int l = l0 + i;
    float v = db;
#pragma unroll
    for (int r = 0; r < Rc; r++) v += dw[r] * dtsb[(k * Rc + r) * Lc + l];
    float dtv = softplusf(v);
    int idx = perm_idx(k, l);
    float xvv = xact[idx * DIc + d];
    float dtx = dtv * xvv;
    const float* Bf = Bsb + (k * Lc + l) * Sc;
#pragma unroll
    for (int s = 0; s < Sc; s++) {
      float da = __expf(dtv * A[s]);
      pA[s] *= da;
      aB[s] = da * aB[s] + dtx * Bf[s];
    }
  }
  // lane-major [k][ch][s][d] stores: coalesced
  float* sa = sumA + ((k * NCH + ch) * Sc) * DIc + d;
  float* sb = sumB + ((k * NCH + ch) * Sc) * DIc + d;
#pragma unroll
  for (int s = 0; s < Sc; s++) { sa[s * DIc] = pA[s]; sb[s * DIc] = aB[s]; }
}

DEV void ph_mid(int slot, int bu, int tid, float* ws) {
  int gid = bu * 256 + tid;
  float* base = ws + (size_t)slot * SLOTF;
  const float* sumA = base + OFF_SUMA;
  const float* sumB = base + OFF_SUMB;
  float* h0 = base + OFF_H0;
  int d = gid & (DIc - 1);
  int s = (gid >> 7) & (Sc - 1);
  int k = gid >> 11;
  float h = 0.f;
  for (int ch = 0; ch < NCH; ch++) {
    int idx = ((k * NCH + ch) * Sc + s) * DIc + d;
    h0[idx] = h;
    h = sumA[idx] * h + sumB[idx];
  }
}

DEV void ph_scan2(int slot, int bu, int tid, const Params& p, float* ws) {
  int gid = bu * 256 + tid;
  int branch = (slot >= 4) ? 0 : 1;
  float* base = ws + (size_t)slot * SLOTF;
  const float* xact = base + OFF_XACT;
  const float* Bsb  = base + OFF_BS;
  const float* Csb  = base + OFF_CS;
  const float* dtsb = base + OFF_DTS;
  const float* h0b  = base + OFF_H0;
  float* yb = base + OFF_Y;
  int d = gid & (DIc - 1);
  int k = (gid >> 7) & 3;
  int ch = gid >> 9;
  int bk = branch * Kc + k;
  const float* AT   = ws + OFF_TW + TW_AT;
  const float* dtwT = ws + OFF_TW + TW_DTW;
  float A[Sc];
#pragma unroll
  for (int s = 0; s < Sc; s++) A[s] = -__expf(AT[(bk * 16 + s) * 128 + d]);
  float dw[Rc];
#pragma unroll
  for (int r = 0; r < Rc; r++) dw[r] = dtwT[(bk * 4 + r) * 128 + d];
  float db = p.dt_b[bk * DIc + d];
  float h[Sc];
  const float* hp = h0b + ((k * NCH + ch) * Sc) * DIc + d;
#pragma unroll
  for (int s = 0; s < Sc; s++) h[s] = hp[s * DIc];
  float Dv = p.Ds[bk * DIc + d];
  int l0 = ch * CHL;
  for (int i = 0; i < CHL; i++) {
    int l = l0 + i;
    float v = db;
#pragma unroll
    for (int r = 0; r < Rc; r++) v += dw[r] * dtsb[(k * Rc + r) * Lc + l];
    float dtv = softplusf(v);
    int idx = perm_idx(k, l);
    float xvv = xact[idx * DIc + d];
    float dtx = dtv * xvv;
    const float* Bf = Bsb + (k * Lc + l) * Sc;
    const float* Cf = Csb + (k * Lc + l) * Sc;
    float acc = 0.f;
#pragma unroll
    for (int s = 0; s < Sc; s++) {
      float da = __expf(dtv * A[s]);
      h[s] = da * h[s] + dtx * Bf[s];
      acc += h[s] * Cf[s];
    }
    yb[(k * Lc + l) * DIc + d] = acc + Dv * xvv;
  }
}

DEV void ph_out_bias(int slot, int blk, int tid, const Params& p, float* ws, float* sm) {
  float (*yy)[DIc] = (float(*)[DIc])sm;
  float (*ml)[DIc] = (float(*)[DIc])(sm + 512);
  float* mnv = sm + 1280;
  float* isv = sm + 1284;
  float* base = ws + (size_t)slot * SLOTF;
  const float* yb = base + OFF_Y;
  const float* zb = base + OFF_Z;
  const float* owT = ws + OFF_TW + TW_OW + 128 * 64;  // branch 1
  float* biasb = ws + OFF_BIAS;
  int l0 = blk * 4;
  for (int it = tid; it < 4 * DIc; it += 256) {
    int d = it & (DIc - 1), pp = it >> 7;
    int l = l0 + pp;
    int www = l % 48, hh = l / 48;
    int lr = l, lcx = www * 48 + hh;
    float v = yb[(0 * Lc + lr) * DIc + d] + yb[(1 * Lc + lcx) * DIc + d] +
              yb[(2 * Lc + (Lc - 1 - lr)) * DIc + d] +
              yb[(3 * Lc + (Lc - 1 - lcx)) * DIc + d];
    yy[pp][d] = v;
  }
  __syncthreads();
  {
    int wv = tid >> 6, c = tid & 63;
    float a = yy[wv][c], b = yy[wv][c + 64];
    float s1 = wsum(a + b);
    float s2 = wsum(a * a + b * b);
    float mu = s1 * (1.f / 128.f);
    float var = s2 * (1.f / 128.f) - mu * mu;
    if (c == 0) { mnv[wv] = mu; isv[wv] = rsqrtf(var + 1e-6f); }
  }
  __syncthreads();
  for (int it = tid; it < 4 * DIc; it += 256) {
    int d = it & (DIc - 1), pp = it >> 7;
    int l = l0 + pp;
    float m = (yy[pp][d] - mnv[pp]) * isv[pp] * p.onw[DIc + d] + p.onb[DIc + d];
    float zv = zb[l * DIc + d];
    ml[pp][d] = m * zv * sigmoidf(zv);
  }
  __syncthreads();
  {
    int pp = tid >> 6, c = tid & 63;
    int l = l0 + pp;
    float acc = p.ob[Cc + c];
    for (int d2 = 0; d2 < DIc; d2++) acc += owT[d2 * 64 + c] * ml[pp][d2];
    biasb[(slot * Lc + l) * Cc + c] = acc;
  }
}

DEV void ph_out_s(int blk, int tid, const Params& p, int targ, int fuse, int finalw,
                  const float* curb, float* nxtb, float* ws, float* sm) {
  float (*yy)[DIc] = (float(*)[DIc])sm;
  float (*ml)[DIc] = (float(*)[DIc])(sm + 512);
  float (*xvs)[64] = (float(*)[64])(sm + 1024);
  float* mnv = sm + 1280;
  float* isv = sm + 1284;
  float* base = ws + (size_t)4 * SLOTF;
  const float* yb = base + OFF_Y;
  const float* zb = base + OFF_Z;
  float* xcpre = base + OFF_XCPRE;
  float* zbuf  = base + OFF_Z;
  const float* owT  = ws + OFF_TW + TW_OW;    // branch 0
  const float* inwT = ws + OFF_TW + TW_INW;   // branch 0
  const float* biasb = ws + OFF_BIAS;
  int l0 = blk * 4;
  for (int it = tid; it < 4 * DIc; it += 256) {
    int d = it & (DIc - 1), pp = it >> 7;
    int l = l0 + pp;
    int www = l % 48, hh = l / 48;
    int lr = l, lcx = www * 48 + hh;
    float v = yb[(0 * Lc + lr) * DIc + d] + yb[(1 * Lc + lcx) * DIc + d] +
              yb[(2 * Lc + (Lc - 1 - lr)) * DIc + d] +
              yb[(3 * Lc + (Lc - 1 - lcx)) * DIc + d];
    yy[pp][d] = v;
  }
  __syncthreads();
  {
    int wv = tid >> 6, c = tid & 63;
    float a = yy[wv][c], b = yy[wv][c + 64];
    float s1 = wsum(a + b);
    float s2 = wsum(a * a + b * b);
    float mu = s1 * (1.f / 128.f);
    float var = s2 * (1.f / 128.f) - mu * mu;
    if (c == 0) { mnv[wv] = mu; isv[wv] = rsqrtf(var + 1e-6f); }
  }
  __syncthreads();
  for (int it = tid; it < 4 * DIc; it += 256) {
    int d = it & (DIc - 1), pp = it >> 7;
    int l = l0 + pp;
    float m = (yy[pp][d] - mnv[pp]) * isv[pp] * p.onw[d] + p.onb[d];
    float zv = zb[l * DIc + d];
    ml[pp][d] = m * zv * sigmoidf(zv);
  }
  __syncthreads();
  {
    int pp = tid >> 6, c = tid & 63;
    int l = l0 + pp;
    float acc = p.ob[c];
    for (int d2 = 0; d2 < DIc; d2++) acc += owT[d2 * 64 + c] * ml[pp][d2];
    float cv = curb[l * Cc + c];
    float nv = cv * __expf(acc) + biasb[(targ * Lc + l) * Cc + c];
    nxtb[l * Cc + c] = nv;
    if (finalw) p.outp[c * Lc + l] = nv;
    if (fuse) {
      float mp = wmax(cv);
      float sp = wsum(__expf(cv - mp));
      float lp = cv - mp - __logf(sp);
      float mq = wmax(nv);
      float sq = wsum(__expf(nv - mq));
      float lq = nv - mq - __logf(sq);
      xvs[pp][c] = __expf(lp) * (lp - lq);
    }
  }
  if (fuse) {
    __syncthreads();
    int d = tid;
    float acc[4] = {0.f, 0.f, 0.f, 0.f};
    for (int cc = 0; cc < Cc; cc++) {
      float wval = inwT[cc * 256 + d];
#pragma unroll
      for (int pp = 0; pp < 4; pp++) acc[pp] += wval * xvs[pp][cc];
    }
    float bv = p.in_b[d];
    if (d < DIc) {
#pragma unroll
      for (int pp = 0; pp < 4; pp++) xcpre[(l0 + pp) * DIc + d] = acc[pp] + bv;
    } else {
      int dd = d - DIc;
#pragma unroll
      for (int pp = 0; pp < 4; pp++) zbuf[(l0 + pp) * DIc + dd] = acc[pp] + bv;
    }
  }
}

// ---------------------------------------------------------------------------
// PATH A: whole model in one cooperative kernel (grid-stride phases).
__global__ __launch_bounds__(256) void k_all(Params p) {
  cg::grid_group grid = cg::this_grid();
  __shared__ float sm[1344];
  int tid = threadIdx.x;
  float* ws = p.ws;

  for (int bu = blockIdx.x; bu < 720; bu += gridDim.x) {
    if (bu < 144) ph_transpose(bu, tid, p, ws + OFF_TW);
    else ph_prep(bu - 144, tid, p, ws);
  }
  grid.sync();
  for (int bu = blockIdx.x; bu < 288 * 5; bu += gridDim.x) {
    __syncthreads();
    ph_inproj(bu / 288, bu % 288, tid, p, ws, sm);
  }
  grid.sync();
  for (int bu = blockIdx.x; bu < 576 * 5; bu += gridDim.x) {
    __syncthreads();
    ph_conv(bu / 576, bu % 576, tid, p, ws, sm);
  }
  grid.sync();
  for (int bu = blockIdx.x; bu < 288 * 5; bu += gridDim.x)
    ph_scan1(bu / 288, bu % 288, tid, p, ws);
  grid.sync();
  for (int bu = blockIdx.x; bu < 32 * 5; bu += gridDim.x)
    ph_mid(bu / 32, bu % 32, tid, ws);
  grid.sync();
  for (int bu = blockIdx.x; bu < 288 * 5; bu += gridDim.x)
    ph_scan2(bu / 288, bu % 288, tid, p, ws);
  grid.sync();
  for (int bu = blockIdx.x; bu < 576 * 4; bu += gridDim.x) {
    __syncthreads();
    ph_out_bias(bu / 576, bu % 576, tid, p, ws, sm);
  }
  grid.sync();

  float* b1 = ws + OFF_B1;
  float* b2 = ws + OFF_B2;
  for (int bu = blockIdx.x; bu < 576; bu += gridDim.x) {
    __syncthreads();
    ph_out_s(bu, tid, p, 0, 1, 0, b1, b2, ws, sm);
  }
  grid.sync();

  for (int t = 1; t < Tc; t++) {
    const float* curb = (t & 1) ? b2 : b1;
    float* nxtb       = (t & 1) ? b1 : b2;
    for (int bu = blockIdx.x; bu < 576; bu += gridDim.x) {
      __syncthreads();
      ph_conv(4, bu, tid, p, ws, sm);
    }
    grid.sync();
    for (int bu = blockIdx.x; bu < 288; bu += gridDim.x)
      ph_scan1(4, bu, tid, p, ws);
    grid.sync();
    for (int bu = blockIdx.x; bu < 32; bu += gridDim.x)
      ph_mid(4, bu, tid, ws);
    grid.sync();
    for (int bu = blockIdx.x; bu < 288; bu += gridDim.x)
      ph_scan2(4, bu, tid, p, ws);
    grid.sync();
    for (int bu = blockIdx.x; bu < 576; bu += gridDim.x) {
      __syncthreads();
      ph_out_s(bu, tid, p, t, (t == Tc - 1) ? 0 : 1, (t == Tc - 1) ? 1 : 0,
               curb, nxtb, ws, sm);
    }
    if (t != Tc - 1) grid.sync();
  }
}

// ---------------------------------------------------------------------------
// PATH B fallback: thin wrappers over the same phase bodies (round-6 structure).
__global__ __launch_bounds__(256) void g_phase0(Params p) {
  int bu = blockIdx.x;
  if (bu < 144) ph_transpose(bu, threadIdx.x, p, p.ws + OFF_TW);
  else ph_prep(bu - 144, threadIdx.x, p, p.ws);
}
__global__ __launch_bounds__(256) void g_inproj(Params p) {
  __shared__ float sm[1344];
  ph_inproj(blockIdx.y, blockIdx.x, threadIdx.x, p, p.ws, sm);
}
__global__ __launch_bounds__(256) void g_conv(Params p, int slot_base) {
  __shared__ float sm[1344];
  ph_conv(slot_base + blockIdx.y, blockIdx.x, threadIdx.x, p, p.ws, sm);
}
__global__ __launch_bounds__(256) void g_scan1(Params p, int slot_base) {
  ph_scan1(slot_base + blockIdx.y, blockIdx.x, threadIdx.x, p, p.ws);
}
__global__ __launch_bounds__(256) void g_mid(Params p, int slot_base) {
  ph_mid(slot_base + blockIdx.y, blockIdx.x, threadIdx.x, p.ws);
}
__global__ __launch_bounds__(256) void g_scan2(Params p, int slot_base) {
  ph_scan2(slot_base + blockIdx.y, blockIdx.x, threadIdx.x, p, p.ws);
}
__global__ __launch_bounds__(256) void g_out_bias(Params p) {
  __shared__ float sm[1344];
  ph_out_bias(blockIdx.y, blockIdx.x, threadIdx.x, p, p.ws, sm);
}
__global__ __launch_bounds__(256) void g_out_s(Params p, int targ, int fuse, int finalw,
                                               const float* curb, float* nxtb) {
  __shared__ float sm[1344];
  ph_out_s(blockIdx.x, threadIdx.x, p, targ, fuse, finalw, curb, nxtb, p.ws, sm);
}

// ---------------------------------------------------------------------------
extern "C" void kernel_launch(void* const* d_in, const int* in_sizes, int n_in,
                              void* d_out, int out_size, void* d_ws, size_t ws_size,
                              hipStream_t stream) {
  (void)in_sizes; (void)n_in; (void)out_size; (void)ws_size;
  Params p;
  p.img    = (const float*)d_in[0];
  p.dz     = (const float*)d_in[1];
  p.sigma  = (const float*)d_in[2];
  p.in_w   = (const float*)d_in[3];
  p.in_b   = (const float*)d_in[4];
  p.conv_w = (const float*)d_in[5];
  p.conv_b = (const float*)d_in[6];
  p.xp_w   = (const float*)d_in[7];
  p.dt_w   = (const float*)d_in[8];
  p.dt_b   = (const float*)d_in[9];
  p.A_logs = (const float*)d_in[10];
  p.Ds     = (const float*)d_in[11];
  p.onw    = (const float*)d_in[12];
  p.onb    = (const float*)d_in[13];
  p.ow     = (const float*)d_in[14];
  p.ob     = (const float*)d_in[15];
  p.niw    = (const float*)d_in[16];
  p.nib    = (const float*)d_in[17];
  p.ndw    = (const float*)d_in[18];
  p.ndb    = (const float*)d_in[19];
  p.outp   = (float*)d_out;
  p.ws     = (float*)d_ws;

  // PATH A: cooperative, grid sized by the runtime's own occupancy answer.
  bool coop_ok = false;
  int blocks_per_cu = 0;
  hipError_t qe = hipOccupancyMaxActiveBlocksPerMultiprocessor(&blocks_per_cu, k_all,
                                                               256, 0);
  if (qe == hipSuccess && blocks_per_cu > 0) {
    int grid = blocks_per_cu * 256;
    if (grid > 1024) grid = 1024;
    void* args[] = { &p };
    hipError_t le = hipLaunchCooperativeKernel((const void*)k_all, dim3(grid),
                                               dim3(256), args, 0, stream);
    coop_ok = (le == hipSuccess);
  }
  (void)hipGetLastError();  // clear any launch-rejection state

  if (!coop_ok) {
    // PATH B: multi-launch fallback (identical math via shared phase bodies).
    hipLaunchKernelGGL(g_phase0, dim3(720), dim3(256), 0, stream, p);
    hipLaunchKernelGGL(g_inproj, dim3(288, 5), dim3(256), 0, stream, p);
    hipLaunchKernelGGL(g_conv, dim3(576, 5), dim3(256), 0, stream, p, 0);
    hipLaunchKernelGGL(g_scan1, dim3(288, 5), dim3(256), 0, stream, p, 0);
    hipLaunchKernelGGL(g_mid, dim3(32, 5), dim3(256), 0, stream, p, 0);
    hipLaunchKernelGGL(g_scan2, dim3(288, 5), dim3(256), 0, stream, p, 0);
    hipLaunchKernelGGL(g_out_bias, dim3(576, 4), dim3(256), 0, stream, p);
    float* b1 = p.ws + OFF_B1;
    float* b2 = p.ws + OFF_B2;
    hipLaunchKernelGGL(g_out_s, dim3(576), dim3(256), 0, stream, p, 0, 1, 0,
                       (const float*)b1, b2);
    for (int t = 1; t < Tc; t++) {
      const float* curb = (t & 1) ? b2 : b1;
      float* nxtb       = (t & 1) ? b1 : b2;
      hipLaunchKernelGGL(g_conv, dim3(576, 1), dim3(256), 0, stream, p, 4);
      hipLaunchKernelGGL(g_scan1, dim3(288, 1), dim3(256), 0, stream, p, 4);
      hipLaunchKernelGGL(g_mid, dim3(32, 1), dim3(256), 0, stream, p, 4);
      hipLaunchKernelGGL(g_scan2, dim3(288, 1), dim3(256), 0, stream, p, 4);
      hipLaunchKernelGGL(g_out_s, dim3(576), dim3(256), 0, stream, p,
                         t, (t == Tc - 1) ? 0 : 1, (t == Tc - 1) ? 1 : 0, curb, nxtb);
    }
  }
}

// Round 9
// 588.115 us; speedup vs baseline: 2.4014x; 2.4014x over previous
//
#include <hip/hip_runtime.h>

#define DEV __device__ __forceinline__

// Problem constants
constexpr int Cc = 64, DIc = 128, Sc = 16, Rc = 4, Kc = 4;
constexpr int Lc = 2304, Tc = 4;
constexpr int NCH = 288, CHL = 8;   // 288 chunks of length 8 (shorter serial chain)

// Workspace layout (float offsets). 5 slots: 0-3 = bias branch t=0..3, 4 = s-branch.
// Total ~194 MB (ws_size = 268 MB, measured via harness fill counters).
constexpr int OFF_XCPRE = 0;              // L*DI  [l][d]
constexpr int OFF_Z     = 294912;         // L*DI  [l][d]
constexpr int OFF_XACT  = 589824;         // L*DI  [l][d]
constexpr int OFF_DTS   = 884736;         // K*R*L [k][r][pos]
constexpr int OFF_BS    = 921600;         // K*L*S [k][pos][s]
constexpr int OFF_CS    = 1069056;        // K*L*S
constexpr int OFF_Y     = 1216512;        // K*L*DI [k][pos][d]
constexpr int OFF_SUMA  = 2396160;        // K*NCH*S*DI (lane-major in d)
constexpr int OFF_SUMB  = 4755456;        // K*NCH*S*DI
constexpr int OFF_H0    = 7114752;        // K*NCH*S*DI
constexpr int SLOTF     = 9474048;
constexpr int OFF_B1    = 5 * SLOTF;      // L*C state buffers [l][c]
constexpr int OFF_B2    = OFF_B1 + Lc * Cc;
constexpr int OFF_BIAS  = OFF_B2 + Lc * Cc;       // T*L*C [t][l][c]
// Lane-major transposed weights:
constexpr int OFF_TW    = OFF_BIAS + Tc * Lc * Cc;
constexpr int TW_INW  = 0;        // [2][64][256]
constexpr int TW_XPW  = 32768;    // [2][128][144]
constexpr int TW_OW   = 69632;    // [2][128][64]
constexpr int TW_CW   = 86016;    // [2][9][128]
constexpr int TW_AT   = 88320;    // [2][4][16][128]
constexpr int TW_DTW  = 104704;   // [2][4][4][128]

struct Params {
  const float *img, *dz, *sigma, *in_w, *in_b, *conv_w, *conv_b, *xp_w, *dt_w,
              *dt_b, *A_logs, *Ds, *onw, *onb, *ow, *ob, *niw, *nib, *ndw, *ndb;
  float* outp;
  float* ws;
};

DEV float wsum(float v) {
#pragma unroll
  for (int m = 32; m; m >>= 1) v += __shfl_xor(v, m, 64);
  return v;
}
DEV float wmax(float v) {
#pragma unroll
  for (int m = 32; m; m >>= 1) v = fmaxf(v, __shfl_xor(v, m, 64));
  return v;
}
DEV float sigmoidf(float x) { return 1.f / (1.f + __expf(-x)); }
DEV float softplusf(float v) { return (v > 20.f) ? v : __logf(1.f + __expf(v)); }

// scan-position -> row-major pixel index, per direction
DEV int perm_idx(int k, int l) {
  if (k == 0) return l;
  if (k == 1) return (l % 48) * 48 + l / 48;
  if (k == 2) return Lc - 1 - l;
  int pp = Lc - 1 - l;
  return (pp % 48) * 48 + pp / 48;
}

// ---------------------------------------------------------------------------
// one-time: transpose weights into lane-major layouts. grid 144.
__global__ __launch_bounds__(256) void g_transpose(Params p) {
  float* tw = p.ws + OFF_TW;
  int i = blockIdx.x * 256 + threadIdx.x;
  if (i < 32768) {  // inwT
    int d = i & 255, cc = (i >> 8) & 63, b = i >> 14;
    tw[TW_INW + i] = p.in_w[(b * 256 + d) * 64 + cc];
  }
  if (i < 36864) {  // xpwT
    int kr = i % 144, cc = (i / 144) & 127, b = i / (144 * 128);
    tw[TW_XPW + i] = p.xp_w[(b * 144 + kr) * 128 + cc];
  }
  if (i < 16384) {  // owT
    int c = i & 63, d = (i >> 6) & 127, b = i >> 13;
    tw[TW_OW + i] = p.ow[(b * 64 + c) * 128 + d];
  }
  if (i < 2304) {   // cwT
    int d = i & 127, kk = (i >> 7) % 9, b = i / 1152;
    tw[TW_CW + i] = p.conv_w[(b * 128 + d) * 9 + kk];
  }
  if (i < 16384) {  // AT
    int d = i & 127, bks = i >> 7;
    int s = bks & 15, bk = bks >> 4;
    tw[TW_AT + i] = p.A_logs[(bk * 128 + d) * 16 + s];
  }
  if (i < 4096) {   // dtwT
    int d = i & 127, bkr = i >> 7;
    int r = bkr & 3, bk = bkr >> 2;
    tw[TW_DTW + i] = p.dt_w[(bk * 128 + d) * 4 + r];
  }
}

// ---------------------------------------------------------------------------
// mega input projection, grid (288, 5). slots 0-3: x = LN_c(img[slot]) (branch 1);
// slot 4: fused prep — pv = LN_c(dz), cv = pv*exp(sigma) -> B1, x = KL(cv, pv).
__global__ __launch_bounds__(256) void g_inproj(Params p) {
  __shared__ float xv[8][64];
  int tid = threadIdx.x;
  int slot = blockIdx.y;
  int branch = (slot >= 4) ? 0 : 1;
  float* ws = p.ws;
  float* base = ws + (size_t)slot * SLOTF;
  float* xcpre = base + OFF_XCPRE;
  float* zbuf  = base + OFF_Z;
  const float* wT = ws + OFF_TW + TW_INW + branch * 64 * 256;
  int l0 = blockIdx.x * 8;
  int wv = tid >> 6, c = tid & 63;
#pragma unroll
  for (int q = 0; q < 2; q++) {
    int pp = wv * 2 + q;
    int l = l0 + pp;
    float x;
    if (branch == 1) {
      float v = p.img[(slot * Cc + c) * Lc + l];
      float mu = wsum(v) * (1.f / 64.f);
      float var = wsum(v * v) * (1.f / 64.f) - mu * mu;
      x = (v - mu) * rsqrtf(var + 1e-6f) * p.niw[c] + p.nib[c];
    } else {
      // fused prep: prev = LN_c(dz), cur = prev*exp(sigma)
      float v = p.dz[c * Lc + l];
      float mu = wsum(v) * (1.f / 64.f);
      float var = wsum(v * v) * (1.f / 64.f) - mu * mu;
      float pv = (v - mu) * rsqrtf(var + 1e-6f) * p.ndw[c] + p.ndb[c];
      float cv = pv * __expf(p.sigma[c * Lc + l]);
      (ws + OFF_B1)[l * Cc + c] = cv;
      // KL(cur=cv, prev=pv), wave-local over 64 channels
      float mp = wmax(pv);
      float sp = wsum(__expf(pv - mp));
      float lp = pv - mp - __logf(sp);
      float mq = wmax(cv);
      float sq = wsum(__expf(cv - mq));
      float lq = cv - mq - __logf(sq);
      x = __expf(lp) * (lp - lq);
    }
    xv[pp][c] = x;
  }
  __syncthreads();
  int d = tid;
  float acc[8];
#pragma unroll
  for (int q = 0; q < 8; q++) acc[q] = 0.f;
  for (int cc = 0; cc < Cc; cc++) {
    float wval = wT[cc * 256 + d];
#pragma unroll
    for (int q = 0; q < 8; q++) acc[q] += wval * xv[q][cc];
  }
  float bv = p.in_b[branch * 2 * DIc + d];
  if (d < DIc) {
#pragma unroll
    for (int q = 0; q < 8; q++) xcpre[(l0 + q) * DIc + d] = acc[q] + bv;
  } else {
    int dd = d - DIc;
#pragma unroll
    for (int q = 0; q < 8; q++) zbuf[(l0 + q) * DIc + dd] = acc[q] + bv;
  }
}

// ---------------------------------------------------------------------------
// depthwise conv3x3 + silu -> xact; xp proj -> dts/Bs/Cs. grid (576, nslots).
__global__ __launch_bounds__(256) void g_conv(Params p, int slot_base) {
  __shared__ float xv[4][DIc];
  int tid = threadIdx.x;
  int slot = slot_base + blockIdx.y;
  int branch = (slot >= 4) ? 0 : 1;
  float* ws = p.ws;
  float* base = ws + (size_t)slot * SLOTF;
  float* xcpre = base + OFF_XCPRE;
  float* xact  = base + OFF_XACT;
  float* dtsb  = base + OFF_DTS;
  float* Bsb   = base + OFF_BS;
  float* Csb   = base + OFF_CS;
  const float* cwT  = ws + OFF_TW + TW_CW + branch * 9 * 128;
  const float* xpwT = ws + OFF_TW + TW_XPW + branch * 128 * 144;
  int h = blockIdx.x / 12;
  int w0 = (blockIdx.x % 12) * 4;
  for (int it = tid; it < 4 * DIc; it += 256) {
    int d = it & (DIc - 1);
    int pp = it >> 7;
    int w = w0 + pp;
    float acc = 0.f;
#pragma unroll
    for (int kh = 0; kh < 3; kh++) {
      int hh = h + kh - 1;
      if ((unsigned)hh < 48u) {
#pragma unroll
        for (int kw = 0; kw < 3; kw++) {
          int wp = w + kw - 1;
          if ((unsigned)wp < 48u)
            acc += cwT[(kh * 3 + kw) * 128 + d] * xcpre[(hh * 48 + wp) * DIc + d];
        }
      }
    }
    float v = acc + p.conv_b[branch * DIc + d];
    float s = v * sigmoidf(v);
    xv[pp][d] = s;
    xact[(h * 48 + w) * DIc + d] = s;
  }
  __syncthreads();
  if (tid < Kc * 36) {
    int k = tid / 36, r = tid % 36;
    float acc[4] = {0.f, 0.f, 0.f, 0.f};
    for (int cc = 0; cc < DIc; cc++) {
      float wvv = xpwT[cc * 144 + tid];
#pragma unroll
      for (int pp = 0; pp < 4; pp++) acc[pp] += wvv * xv[pp][cc];
    }
#pragma unroll
    for (int pp = 0; pp < 4; pp++) {
      int w = w0 + pp;
      int lr = h * 48 + w, lcx = w * 48 + h;
      int pos = (k == 0) ? lr : (k == 1) ? lcx : (k == 2) ? (Lc - 1 - lr) : (Lc - 1 - lcx);
      if (r < Rc) dtsb[(k * Rc + r) * Lc + pos] = acc[pp];
      else if (r < Rc + Sc) Bsb[(k * Lc + pos) * Sc + (r - Rc)] = acc[pp];
      else Csb[(k * Lc + pos) * Sc + (r - Rc - Sc)] = acc[pp];
    }
  }
}

// ---------------------------------------------------------------------------
// scan pass 1: per-chunk summaries. thread = (ch,k,d); grid (576, nslots).
__global__ __launch_bounds__(256) void g_scan1(Params p, int slot_base) {
  int gid = blockIdx.x * 256 + threadIdx.x;
  int slot = slot_base + blockIdx.y;
  int branch = (slot >= 4) ? 0 : 1;
  float* ws = p.ws;
  float* base = ws + (size_t)slot * SLOTF;
  const float* xact = base + OFF_XACT;
  const float* Bsb  = base + OFF_BS;
  const float* dtsb = base + OFF_DTS;
  float* sumA = base + OFF_SUMA;
  float* sumB = base + OFF_SUMB;
  int d = gid & (DIc - 1);
  int k = (gid >> 7) & 3;
  int ch = gid >> 9;
  int bk = branch * Kc + k;
  const float* AT   = ws + OFF_TW + TW_AT;
  const float* dtwT = ws + OFF_TW + TW_DTW;
  float A[Sc];
#pragma unroll
  for (int s = 0; s < Sc; s++) A[s] = -__expf(AT[(bk * 16 + s) * 128 + d]);
  float dw[Rc];
#pragma unroll
  for (int r = 0; r < Rc; r++) dw[r] = dtwT[(bk * 4 + r) * 128 + d];
  float db = p.dt_b[bk * DIc + d];
  float pA[Sc], aB[Sc];
#pragma unroll
  for (int s = 0; s < Sc; s++) { pA[s] = 1.f; aB[s] = 0.f; }
  int l0 = ch * CHL;
#pragma unroll
  for (int i = 0; i < CHL; i++) {
    int l = l0 + i;
    float v = db;
#pragma unroll
    for (int r = 0; r < Rc; r++) v += dw[r] * dtsb[(k * Rc + r) * Lc + l];
    float dtv = softplusf(v);
    int idx = perm_idx(k, l);
    float xvv = xact[idx * DIc + d];
    float dtx = dtv * xvv;
    const float* Bf = Bsb + (k * Lc + l) * Sc;
#pragma unroll
    for (int s = 0; s < Sc; s++) {
      float da = __expf(dtv * A[s]);
      pA[s] *= da;
      aB[s] = da * aB[s] + dtx * Bf[s];
    }
  }
  float* sa = sumA + ((k * NCH + ch) * Sc) * DIc + d;
  float* sb = sumB + ((k * NCH + ch) * Sc) * DIc + d;
#pragma unroll
  for (int s = 0; s < Sc; s++) { sa[s * DIc] = pA[s]; sb[s * DIc] = aB[s]; }
}

// ---------------------------------------------------------------------------
// scan mid: sequential combine over chunk summaries -> per-chunk initial state.
// thread = (k,s,d); grid (32, nslots), all loads/stores coalesced in d.
__global__ __launch_bounds__(256) void g_mid(Params p, int slot_base) {
  int gid = blockIdx.x * 256 + threadIdx.x;
  int slot = slot_base + blockIdx.y;
  float* base = p.ws + (size_t)slot * SLOTF;
  const float* sumA = base + OFF_SUMA;
  const float* sumB = base + OFF_SUMB;
  float* h0 = base + OFF_H0;
  int d = gid & (DIc - 1);
  int s = (gid >> 7) & (Sc - 1);
  int k = gid >> 11;
  float h = 0.f;
  for (int ch = 0; ch < NCH; ch++) {
    int idx = ((k * NCH + ch) * Sc + s) * DIc + d;
    h0[idx] = h;
    h = sumA[idx] * h + sumB[idx];
  }
}

// ---------------------------------------------------------------------------
// scan pass 2: load h0, rescan chunk, emit y = h·C + D*x. grid (576, nslots).
__global__ __launch_bounds__(256) void g_scan2(Params p, int slot_base) {
  int gid = blockIdx.x * 256 + threadIdx.x;
  int slot = slot_base + blockIdx.y;
  int branch = (slot >= 4) ? 0 : 1;
  float* ws = p.ws;
  float* base = ws + (size_t)slot * SLOTF;
  const float* xact = base + OFF_XACT;
  const float* Bsb  = base + OFF_BS;
  const float* Csb  = base + OFF_CS;
  const float* dtsb = base + OFF_DTS;
  const float* h0b  = base + OFF_H0;
  float* yb = base + OFF_Y;
  int d = gid & (DIc - 1);
  int k = (gid >> 7) & 3;
  int ch = gid >> 9;
  int bk = branch * Kc + k;
  const float* AT   = ws + OFF_TW + TW_AT;
  const float* dtwT = ws + OFF_TW + TW_DTW;
  float A[Sc];
#pragma unroll
  for (int s = 0; s < Sc; s++) A[s] = -__expf(AT[(bk * 16 + s) * 128 + d]);
  float dw[Rc];
#pragma unroll
  for (int r = 0; r < Rc; r++) dw[r] = dtwT[(bk * 4 + r) * 128 + d];
  float db = p.dt_b[bk * DIc + d];
  float h[Sc];
  const float* hp = h0b + ((k * NCH + ch) * Sc) * DIc + d;
#pragma unroll
  for (int s = 0; s < Sc; s++) h[s] = hp[s * DIc];
  float Dv = p.Ds[bk * DIc + d];
  int l0 = ch * CHL;
#pragma unroll
  for (int i = 0; i < CHL; i++) {
    int l = l0 + i;
    float v = db;
#pragma unroll
    for (int r = 0; r < Rc; r++) v += dw[r] * dtsb[(k * Rc + r) * Lc + l];
    float dtv = softplusf(v);
    int idx = perm_idx(k, l);
    float xvv = xact[idx * DIc + d];
    float dtx = dtv * xvv;
    const float* Bf = Bsb + (k * Lc + l) * Sc;
    const float* Cf = Csb + (k * Lc + l) * Sc;
    float acc = 0.f;
#pragma unroll
    for (int s = 0; s < Sc; s++) {
      float da = __expf(dtv * A[s]);
      h[s] = da * h[s] + dtx * Bf[s];
      acc += h[s] * Cf[s];
    }
    yb[(k * Lc + l) * DIc + d] = acc + Dv * xvv;
  }
}

// ---------------------------------------------------------------------------
// bias-branch epilogue: combine dirs + LN + silu(z) + out-proj -> biasb[slot].
// grid (576, 4).
__global__ __launch_bounds__(256) void g_out_bias(Params p) {
  __shared__ float yy[4][DIc];
  __shared__ float ml[4][DIc];
  __shared__ float mnv[4], isv[4];
  int tid = threadIdx.x;
  int slot = blockIdx.y;
  float* ws = p.ws;
  float* base = ws + (size_t)slot * SLOTF;
  const float* yb = base + OFF_Y;
  const float* zb = base + OFF_Z;
  const float* owT = ws + OFF_TW + TW_OW + 128 * 64;  // branch 1
  float* biasb = ws + OFF_BIAS;
  int l0 = blockIdx.x * 4;
  for (int it = tid; it < 4 * DIc; it += 256) {
    int d = it & (DIc - 1), pp = it >> 7;
    int l = l0 + pp;
    int www = l % 48, hh = l / 48;
    int lr = l, lcx = www * 48 + hh;
    float v = yb[(0 * Lc + lr) * DIc + d] + yb[(1 * Lc + lcx) * DIc + d] +
              yb[(2 * Lc + (Lc - 1 - lr)) * DIc + d] +
              yb[(3 * Lc + (Lc - 1 - lcx)) * DIc + d];
    yy[pp][d] = v;
  }
  __syncthreads();
  {
    int wv = tid >> 6, c = tid & 63;
    float a = yy[wv][c], b = yy[wv][c + 64];
    float s1 = wsum(a + b);
    float s2 = wsum(a * a + b * b);
    float mu = s1 * (1.f / 128.f);
    float var = s2 * (1.f / 128.f) - mu * mu;
    if (c == 0) { mnv[wv] = mu; isv[wv] = rsqrtf(var + 1e-6f); }
  }
  __syncthreads();
  for (int it = tid; it < 4 * DIc; it += 256) {
    int d = it & (DIc - 1), pp = it >> 7;
    int l = l0 + pp;
    float m = (yy[pp][d] - mnv[pp]) * isv[pp] * p.onw[DIc + d] + p.onb[DIc + d];
    float zv = zb[l * DIc + d];
    ml[pp][d] = m * zv * sigmoidf(zv);
  }
  __syncthreads();
  {
    int pp = tid >> 6, c = tid & 63;
    int l = l0 + pp;
    float acc = p.ob[Cc + c];
    for (int d2 = 0; d2 < DIc; d2++) acc += owT[d2 * 64 + c] * ml[pp][d2];
    biasb[(slot * Lc + l) * Cc + c] = acc;
  }
}

// ---------------------------------------------------------------------------
// s-branch epilogue (slot 4, branch 0): combine + LN + silu(z) + out-proj,
// state update; if fuse: KL + in-proj for next round; if finalw: write d_out.
__global__ __launch_bounds__(256) void g_out_s(Params p, int targ, int fuse, int finalw,
                                               const float* curb, float* nxtb) {
  __shared__ float yy[4][DIc];
  __shared__ float ml[4][DIc];
  __shared__ float xvs[4][64];
  __shared__ float mnv[4], isv[4];
  int tid = threadIdx.x;
  float* ws = p.ws;
  float* base = ws + (size_t)4 * SLOTF;
  const float* yb = base + OFF_Y;
  const float* zb = base + OFF_Z;
  float* xcpre = base + OFF_XCPRE;
  float* zbuf  = base + OFF_Z;
  const float* owT  = ws + OFF_TW + TW_OW;    // branch 0
  const float* inwT = ws + OFF_TW + TW_INW;   // branch 0
  const float* biasb = ws + OFF_BIAS;
  int l0 = blockIdx.x * 4;
  for (int it = tid; it < 4 * DIc; it += 256) {
    int d = it & (DIc - 1), pp = it >> 7;
    int l = l0 + pp;
    int www = l % 48, hh = l / 48;
    int lr = l, lcx = www * 48 + hh;
    float v = yb[(0 * Lc + lr) * DIc + d] + yb[(1 * Lc + lcx) * DIc + d] +
              yb[(2 * Lc + (Lc - 1 - lr)) * DIc + d] +
              yb[(3 * Lc + (Lc - 1 - lcx)) * DIc + d];
    yy[pp][d] = v;
  }
  __syncthreads();
  {
    int wv = tid >> 6, c = tid & 63;
    float a = yy[wv][c], b = yy[wv][c + 64];
    float s1 = wsum(a + b);
    float s2 = wsum(a * a + b * b);
    float mu = s1 * (1.f / 128.f);
    float var = s2 * (1.f / 128.f) - mu * mu;
    if (c == 0) { mnv[wv] = mu; isv[wv] = rsqrtf(var + 1e-6f); }
  }
  __syncthreads();
  for (int it = tid; it < 4 * DIc; it += 256) {
    int d = it & (DIc - 1), pp = it >> 7;
    int l = l0 + pp;
    float m = (yy[pp][d] - mnv[pp]) * isv[pp] * p.onw[d] + p.onb[d];
    float zv = zb[l * DIc + d];
    ml[pp][d] = m * zv * sigmoidf(zv);
  }
  __syncthreads();
  {
    int pp = tid >> 6, c = tid & 63;
    int l = l0 + pp;
    float acc = p.ob[c];
    for (int d2 = 0; d2 < DIc; d2++) acc += owT[d2 * 64 + c] * ml[pp][d2];
    float cv = curb[l * Cc + c];
    float nv = cv * __expf(acc) + biasb[(targ * Lc + l) * Cc + c];
    nxtb[l * Cc + c] = nv;
    if (finalw) p.outp[c * Lc + l] = nv;
    if (fuse) {
      float mp = wmax(cv);
      float sp = wsum(__expf(cv - mp));
      float lp = cv - mp - __logf(sp);
      float mq = wmax(nv);
      float sq = wsum(__expf(nv - mq));
      float lq = nv - mq - __logf(sq);
      xvs[pp][c] = __expf(lp) * (lp - lq);
    }
  }
  if (fuse) {
    __syncthreads();
    int d = tid;
    float acc[4] = {0.f, 0.f, 0.f, 0.f};
    for (int cc = 0; cc < Cc; cc++) {
      float wval = inwT[cc * 256 + d];
#pragma unroll
      for (int pp = 0; pp < 4; pp++) acc[pp] += wval * xvs[pp][cc];
    }
    float bv = p.in_b[d];
    if (d < DIc) {
#pragma unroll
      for (int pp = 0; pp < 4; pp++) xcpre[(l0 + pp) * DIc + d] = acc[pp] + bv;
    } else {
      int dd = d - DIc;
#pragma unroll
      for (int pp = 0; pp < 4; pp++) zbuf[(l0 + pp) * DIc + dd] = acc[pp] + bv;
    }
  }
}

// ---------------------------------------------------------------------------
extern "C" void kernel_launch(void* const* d_in, const int* in_sizes, int n_in,
                              void* d_out, int out_size, void* d_ws, size_t ws_size,
                              hipStream_t stream) {
  (void)in_sizes; (void)n_in; (void)out_size; (void)ws_size;
  Params p;
  p.img    = (const float*)d_in[0];
  p.dz     = (const float*)d_in[1];
  p.sigma  = (const float*)d_in[2];
  p.in_w   = (const float*)d_in[3];
  p.in_b   = (const float*)d_in[4];
  p.conv_w = (const float*)d_in[5];
  p.conv_b = (const float*)d_in[6];
  p.xp_w   = (const float*)d_in[7];
  p.dt_w   = (const float*)d_in[8];
  p.dt_b   = (const float*)d_in[9];
  p.A_logs = (const float*)d_in[10];
  p.Ds     = (const float*)d_in[11];
  p.onw    = (const float*)d_in[12];
  p.onb    = (const float*)d_in[13];
  p.ow     = (const float*)d_in[14];
  p.ob     = (const float*)d_in[15];
  p.niw    = (const float*)d_in[16];
  p.nib    = (const float*)d_in[17];
  p.ndw    = (const float*)d_in[18];
  p.ndb    = (const float*)d_in[19];
  p.outp   = (float*)d_out;
  p.ws     = (float*)d_ws;

  // NOTE: cooperative mega-kernel removed — measured 3.4x slower (grid.sync
  // forces cross-XCD L2 flushes: 343 MB HBM traffic vs ~150 MB, VALUBusy 7.6%).

  hipLaunchKernelGGL(g_transpose, dim3(144), dim3(256), 0, stream, p);
  // mega round: bias t=0..3 (slots 0-3) + s-branch t=0 (slot 4, prep fused)
  hipLaunchKernelGGL(g_inproj, dim3(288, 5), dim3(256), 0, stream, p);
  hipLaunchKernelGGL(g_conv, dim3(576, 5), dim3(256), 0, stream, p, 0);
  hipLaunchKernelGGL(g_scan1, dim3(576, 5), dim3(256), 0, stream, p, 0);
  hipLaunchKernelGGL(g_mid, dim3(32, 5), dim3(256), 0, stream, p, 0);
  hipLaunchKernelGGL(g_scan2, dim3(576, 5), dim3(256), 0, stream, p, 0);
  hipLaunchKernelGGL(g_out_bias, dim3(576, 4), dim3(256), 0, stream, p);

  float* b1 = p.ws + OFF_B1;
  float* b2 = p.ws + OFF_B2;
  hipLaunchKernelGGL(g_out_s, dim3(576), dim3(256), 0, stream, p, 0, 1, 0,
                     (const float*)b1, b2);
  for (int t = 1; t < Tc; t++) {
    const float* curb = (t & 1) ? b2 : b1;
    float* nxtb       = (t & 1) ? b1 : b2;
    hipLaunchKernelGGL(g_conv, dim3(576, 1), dim3(256), 0, stream, p, 4);
    hipLaunchKernelGGL(g_scan1, dim3(576, 1), dim3(256), 0, stream, p, 4);
    hipLaunchKernelGGL(g_mid, dim3(32, 1), dim3(256), 0, stream, p, 4);
    hipLaunchKernelGGL(g_scan2, dim3(576, 1), dim3(256), 0, stream, p, 4);
    hipLaunchKernelGGL(g_out_s, dim3(576), dim3(256), 0, stream, p,
                       t, (t == Tc - 1) ? 0 : 1, (t == Tc - 1) ? 1 : 0, curb, nxtb);
  }
}

// Round 10
// 436.603 us; speedup vs baseline: 3.2347x; 1.3470x over previous
//
#include <hip/hip_runtime.h>

#define DEV __device__ __forceinline__

// Problem constants
constexpr int Cc = 64, DIc = 128, Sc = 16, Rc = 4, Kc = 4;
constexpr int Lc = 2304, Tc = 4;
constexpr int NCH = 144, CHL = 16;  // 144 chunks of 16 (mid chain halved vs R9)

// Workspace layout (float offsets). 5 slots: 0-3 = bias branch t=0..3, 4 = s-branch.
constexpr int OFF_XCPRE = 0;              // L*DI  [l][d]
constexpr int OFF_Z     = 294912;         // L*DI  [l][d]
constexpr int OFF_XACT  = 589824;         // L*DI  [l][d]
constexpr int OFF_DTS   = 884736;         // K*R*L [k][r][pos]
constexpr int OFF_BS    = 921600;         // K*L*S [k][pos][s]
constexpr int OFF_CS    = 1069056;        // K*L*S
constexpr int OFF_Y     = 1216512;        // K*L*DI [k][pos][d]
constexpr int OFF_SUMA  = 2396160;        // K*NCH*S*DI (lane-major in d)
constexpr int OFF_SUMB  = 3575808;        // K*NCH*S*DI
constexpr int OFF_H0    = 4755456;        // K*NCH*S*DI
constexpr int SLOTF     = 5935104;
constexpr int OFF_B1    = 5 * SLOTF;      // L*C state buffers [l][c]
constexpr int OFF_B2    = OFF_B1 + Lc * Cc;
constexpr int OFF_BIAS  = OFF_B2 + Lc * Cc;       // T*L*C [t][l][c]
// Lane-major transposed weights:
constexpr int OFF_TW    = OFF_BIAS + Tc * Lc * Cc;
constexpr int TW_INW  = 0;        // [2][64][256]
constexpr int TW_XPW  = 32768;    // [2][128][144]
constexpr int TW_OW   = 69632;    // [2][128][64]
constexpr int TW_CW   = 86016;    // [2][9][128]
constexpr int TW_AT   = 88320;    // [2][4][16][128]
constexpr int TW_DTW  = 104704;   // [2][4][4][128]

struct Params {
  const float *img, *dz, *sigma, *in_w, *in_b, *conv_w, *conv_b, *xp_w, *dt_w,
              *dt_b, *A_logs, *Ds, *onw, *onb, *ow, *ob, *niw, *nib, *ndw, *ndb;
  float* outp;
  float* ws;
};

DEV float wsum(float v) {
#pragma unroll
  for (int m = 32; m; m >>= 1) v += __shfl_xor(v, m, 64);
  return v;
}
DEV float wmax(float v) {
#pragma unroll
  for (int m = 32; m; m >>= 1) v = fmaxf(v, __shfl_xor(v, m, 64));
  return v;
}
DEV float sigmoidf(float x) { return 1.f / (1.f + __expf(-x)); }
DEV float softplusf(float v) { return (v > 20.f) ? v : __logf(1.f + __expf(v)); }

// scan-position -> row-major pixel index, per direction
DEV int perm_idx(int k, int l) {
  if (k == 0) return l;
  if (k == 1) return (l % 48) * 48 + l / 48;
  if (k == 2) return Lc - 1 - l;
  int pp = Lc - 1 - l;
  return (pp % 48) * 48 + pp / 48;
}

// ---------------------------------------------------------------------------
// one-time: transpose weights into lane-major layouts. grid 144.
__global__ __launch_bounds__(256) void g_transpose(Params p) {
  float* tw = p.ws + OFF_TW;
  int i = blockIdx.x * 256 + threadIdx.x;
  if (i < 32768) {  // inwT
    int d = i & 255, cc = (i >> 8) & 63, b = i >> 14;
    tw[TW_INW + i] = p.in_w[(b * 256 + d) * 64 + cc];
  }
  if (i < 36864) {  // xpwT
    int kr = i % 144, cc = (i / 144) & 127, b = i / (144 * 128);
    tw[TW_XPW + i] = p.xp_w[(b * 144 + kr) * 128 + cc];
  }
  if (i < 16384) {  // owT
    int c = i & 63, d = (i >> 6) & 127, b = i >> 13;
    tw[TW_OW + i] = p.ow[(b * 64 + c) * 128 + d];
  }
  if (i < 2304) {   // cwT
    int d = i & 127, kk = (i >> 7) % 9, b = i / 1152;
    tw[TW_CW + i] = p.conv_w[(b * 128 + d) * 9 + kk];
  }
  if (i < 16384) {  // AT
    int d = i & 127, bks = i >> 7;
    int s = bks & 15, bk = bks >> 4;
    tw[TW_AT + i] = p.A_logs[(bk * 128 + d) * 16 + s];
  }
  if (i < 4096) {   // dtwT
    int d = i & 127, bkr = i >> 7;
    int r = bkr & 3, bk = bkr >> 2;
    tw[TW_DTW + i] = p.dt_w[(bk * 128 + d) * 4 + r];
  }
}

// ---------------------------------------------------------------------------
// mega input projection, grid (288, 5). slots 0-3: x = LN_c(img[slot]) (branch 1);
// slot 4: fused prep — pv = LN_c(dz), cv = pv*exp(sigma) -> B1, x = KL(cv, pv).
__global__ __launch_bounds__(256) void g_inproj(Params p) {
  __shared__ float xv[8][64];
  int tid = threadIdx.x;
  int slot = blockIdx.y;
  int branch = (slot >= 4) ? 0 : 1;
  float* ws = p.ws;
  float* base = ws + (size_t)slot * SLOTF;
  float* xcpre = base + OFF_XCPRE;
  float* zbuf  = base + OFF_Z;
  const float* wT = ws + OFF_TW + TW_INW + branch * 64 * 256;
  int l0 = blockIdx.x * 8;
  int wv = tid >> 6, c = tid & 63;
#pragma unroll
  for (int q = 0; q < 2; q++) {
    int pp = wv * 2 + q;
    int l = l0 + pp;
    float x;
    if (branch == 1) {
      float v = p.img[(slot * Cc + c) * Lc + l];
      float mu = wsum(v) * (1.f / 64.f);
      float var = wsum(v * v) * (1.f / 64.f) - mu * mu;
      x = (v - mu) * rsqrtf(var + 1e-6f) * p.niw[c] + p.nib[c];
    } else {
      // fused prep: prev = LN_c(dz), cur = prev*exp(sigma)
      float v = p.dz[c * Lc + l];
      float mu = wsum(v) * (1.f / 64.f);
      float var = wsum(v * v) * (1.f / 64.f) - mu * mu;
      float pv = (v - mu) * rsqrtf(var + 1e-6f) * p.ndw[c] + p.ndb[c];
      float cv = pv * __expf(p.sigma[c * Lc + l]);
      (ws + OFF_B1)[l * Cc + c] = cv;
      float mp = wmax(pv);
      float sp = wsum(__expf(pv - mp));
      float lp = pv - mp - __logf(sp);
      float mq = wmax(cv);
      float sq = wsum(__expf(cv - mq));
      float lq = cv - mq - __logf(sq);
      x = __expf(lp) * (lp - lq);
    }
    xv[pp][c] = x;
  }
  __syncthreads();
  int d = tid;
  float acc[8];
#pragma unroll
  for (int q = 0; q < 8; q++) acc[q] = 0.f;
  for (int cc = 0; cc < Cc; cc++) {
    float wval = wT[cc * 256 + d];
#pragma unroll
    for (int q = 0; q < 8; q++) acc[q] += wval * xv[q][cc];
  }
  float bv = p.in_b[branch * 2 * DIc + d];
  if (d < DIc) {
#pragma unroll
    for (int q = 0; q < 8; q++) xcpre[(l0 + q) * DIc + d] = acc[q] + bv;
  } else {
    int dd = d - DIc;
#pragma unroll
    for (int q = 0; q < 8; q++) zbuf[(l0 + q) * DIc + dd] = acc[q] + bv;
  }
}

// ---------------------------------------------------------------------------
// depthwise conv3x3 + silu -> xact; xp proj -> dts/Bs/Cs. grid (576, nslots).
__global__ __launch_bounds__(256) void g_conv(Params p, int slot_base) {
  __shared__ float xv[4][DIc];
  int tid = threadIdx.x;
  int slot = slot_base + blockIdx.y;
  int branch = (slot >= 4) ? 0 : 1;
  float* ws = p.ws;
  float* base = ws + (size_t)slot * SLOTF;
  float* xcpre = base + OFF_XCPRE;
  float* xact  = base + OFF_XACT;
  float* dtsb  = base + OFF_DTS;
  float* Bsb   = base + OFF_BS;
  float* Csb   = base + OFF_CS;
  const float* cwT  = ws + OFF_TW + TW_CW + branch * 9 * 128;
  const float* xpwT = ws + OFF_TW + TW_XPW + branch * 128 * 144;
  int h = blockIdx.x / 12;
  int w0 = (blockIdx.x % 12) * 4;
  for (int it = tid; it < 4 * DIc; it += 256) {
    int d = it & (DIc - 1);
    int pp = it >> 7;
    int w = w0 + pp;
    float acc = 0.f;
#pragma unroll
    for (int kh = 0; kh < 3; kh++) {
      int hh = h + kh - 1;
      if ((unsigned)hh < 48u) {
#pragma unroll
        for (int kw = 0; kw < 3; kw++) {
          int wp = w + kw - 1;
          if ((unsigned)wp < 48u)
            acc += cwT[(kh * 3 + kw) * 128 + d] * xcpre[(hh * 48 + wp) * DIc + d];
        }
      }
    }
    float v = acc + p.conv_b[branch * DIc + d];
    float s = v * sigmoidf(v);
    xv[pp][d] = s;
    xact[(h * 48 + w) * DIc + d] = s;
  }
  __syncthreads();
  if (tid < Kc * 36) {
    int k = tid / 36, r = tid % 36;
    float acc[4] = {0.f, 0.f, 0.f, 0.f};
    for (int cc = 0; cc < DIc; cc++) {
      float wvv = xpwT[cc * 144 + tid];
#pragma unroll
      for (int pp = 0; pp < 4; pp++) acc[pp] += wvv * xv[pp][cc];
    }
#pragma unroll
    for (int pp = 0; pp < 4; pp++) {
      int w = w0 + pp;
      int lr = h * 48 + w, lcx = w * 48 + h;
      int pos = (k == 0) ? lr : (k == 1) ? lcx : (k == 2) ? (Lc - 1 - lr) : (Lc - 1 - lcx);
      if (r < Rc) dtsb[(k * Rc + r) * Lc + pos] = acc[pp];
      else if (r < Rc + Sc) Bsb[(k * Lc + pos) * Sc + (r - Rc)] = acc[pp];
      else Csb[(k * Lc + pos) * Sc + (r - Rc - Sc)] = acc[pp];
    }
  }
}

// ---------------------------------------------------------------------------
// scan pass 1: per-chunk summaries. thread = (ch,k,d); grid (288, nslots).
__global__ __launch_bounds__(256) void g_scan1(Params p, int slot_base) {
  int gid = blockIdx.x * 256 + threadIdx.x;
  int slot = slot_base + blockIdx.y;
  int branch = (slot >= 4) ? 0 : 1;
  float* ws = p.ws;
  float* base = ws + (size_t)slot * SLOTF;
  const float* xact = base + OFF_XACT;
  const float* Bsb  = base + OFF_BS;
  const float* dtsb = base + OFF_DTS;
  float* sumA = base + OFF_SUMA;
  float* sumB = base + OFF_SUMB;
  int d = gid & (DIc - 1);
  int k = (gid >> 7) & 3;
  int ch = gid >> 9;
  int bk = branch * Kc + k;
  const float* AT   = ws + OFF_TW + TW_AT;
  const float* dtwT = ws + OFF_TW + TW_DTW;
  float A[Sc];
#pragma unroll
  for (int s = 0; s < Sc; s++) A[s] = -__expf(AT[(bk * 16 + s) * 128 + d]);
  float dw[Rc];
#pragma unroll
  for (int r = 0; r < Rc; r++) dw[r] = dtwT[(bk * 4 + r) * 128 + d];
  float db = p.dt_b[bk * DIc + d];
  float pA[Sc], aB[Sc];
#pragma unroll
  for (int s = 0; s < Sc; s++) { pA[s] = 1.f; aB[s] = 0.f; }
  int l0 = ch * CHL;
  for (int i = 0; i < CHL; i++) {
    int l = l0 + i;
    float v = db;
#pragma unroll
    for (int r = 0; r < Rc; r++) v += dw[r] * dtsb[(k * Rc + r) * Lc + l];
    float dtv = softplusf(v);
    int idx = perm_idx(k, l);
    float xvv = xact[idx * DIc + d];
    float dtx = dtv * xvv;
    const float* Bf = Bsb + (k * Lc + l) * Sc;
#pragma unroll
    for (int s = 0; s < Sc; s++) {
      float da = __expf(dtv * A[s]);
      pA[s] *= da;
      aB[s] = da * aB[s] + dtx * Bf[s];
    }
  }
  float* sa = sumA + ((k * NCH + ch) * Sc) * DIc + d;
  float* sb = sumB + ((k * NCH + ch) * Sc) * DIc + d;
#pragma unroll
  for (int s = 0; s < Sc; s++) { sa[s * DIc] = pA[s]; sb[s * DIc] = aB[s]; }
}

// ---------------------------------------------------------------------------
// scan mid: serial combine over 144 chunk summaries -> per-chunk initial state.
// thread = (k,s,d); grid (32, nslots). Unrolled x16: 16 independent load-pairs
// in flight per group, then the dependent fma chain -> 9 waits instead of 144.
__global__ __launch_bounds__(256) void g_mid(Params p, int slot_base) {
  int gid = blockIdx.x * 256 + threadIdx.x;
  int slot = slot_base + blockIdx.y;
  float* base = p.ws + (size_t)slot * SLOTF;
  const float* sumA = base + OFF_SUMA;
  const float* sumB = base + OFF_SUMB;
  float* h0 = base + OFF_H0;
  int d = gid & (DIc - 1);
  int s = (gid >> 7) & (Sc - 1);
  int k = gid >> 11;
  float h = 0.f;
  for (int g = 0; g < NCH / 16; g++) {
    float a[16], b[16];
#pragma unroll
    for (int j = 0; j < 16; j++) {
      int idx = ((k * NCH + g * 16 + j) * Sc + s) * DIc + d;
      a[j] = sumA[idx];
      b[j] = sumB[idx];
    }
#pragma unroll
    for (int j = 0; j < 16; j++) {
      int idx = ((k * NCH + g * 16 + j) * Sc + s) * DIc + d;
      h0[idx] = h;
      h = a[j] * h + b[j];
    }
  }
}

// ---------------------------------------------------------------------------
// scan pass 2: load h0, rescan chunk, emit y = h·C + D*x. grid (288, nslots).
__global__ __launch_bounds__(256) void g_scan2(Params p, int slot_base) {
  int gid = blockIdx.x * 256 + threadIdx.x;
  int slot = slot_base + blockIdx.y;
  int branch = (slot >= 4) ? 0 : 1;
  float* ws = p.ws;
  float* base = ws + (size_t)slot * SLOTF;
  const float* xact = base + OFF_XACT;
  const float* Bsb  = base + OFF_BS;
  const float* Csb  = base + OFF_CS;
  const float* dtsb = base + OFF_DTS;
  const float* h0b  = base + OFF_H0;
  float* yb = base + OFF_Y;
  int d = gid & (DIc - 1);
  int k = (gid >> 7) & 3;
  int ch = gid >> 9;
  int bk = branch * Kc + k;
  const float* AT   = ws + OFF_TW + TW_AT;
  const float* dtwT = ws + OFF_TW + TW_DTW;
  float A[Sc];
#pragma unroll
  for (int s = 0; s < Sc; s++) A[s] = -__expf(AT[(bk * 16 + s) * 128 + d]);
  float dw[Rc];
#pragma unroll
  for (int r = 0; r < Rc; r++) dw[r] = dtwT[(bk * 4 + r) * 128 + d];
  float db = p.dt_b[bk * DIc + d];
  float h[Sc];
  const float* hp = h0b + ((k * NCH + ch) * Sc) * DIc + d;
#pragma unroll
  for (int s = 0; s < Sc; s++) h[s] = hp[s * DIc];
  float Dv = p.Ds[bk * DIc + d];
  int l0 = ch * CHL;
  for (int i = 0; i < CHL; i++) {
    int l = l0 + i;
    float v = db;
#pragma unroll
    for (int r = 0; r < Rc; r++) v += dw[r] * dtsb[(k * Rc + r) * Lc + l];
    float dtv = softplusf(v);
    int idx = perm_idx(k, l);
    float xvv = xact[idx * DIc + d];
    float dtx = dtv * xvv;
    const float* Bf = Bsb + (k * Lc + l) * Sc;
    const float* Cf = Csb + (k * Lc + l) * Sc;
    float acc = 0.f;
#pragma unroll
    for (int s = 0; s < Sc; s++) {
      float da = __expf(dtv * A[s]);
      h[s] = da * h[s] + dtx * Bf[s];
      acc += h[s] * Cf[s];
    }
    yb[(k * Lc + l) * DIc + d] = acc + Dv * xvv;
  }
}

// ---------------------------------------------------------------------------
// bias-branch epilogue: combine dirs + LN + silu(z) + out-proj -> biasb[slot].
// grid (576, 4).
__global__ __launch_bounds__(256) void g_out_bias(Params p) {
  __shared__ float yy[4][DIc];
  __shared__ float ml[4][DIc];
  __shared__ float mnv[4], isv[4];
  int tid = threadIdx.x;
  int slot = blockIdx.y;
  float* ws = p.ws;
  float* base = ws + (size_t)slot * SLOTF;
  const float* yb = base + OFF_Y;
  const float* zb = base + OFF_Z;
  const float* owT = ws + OFF_TW + TW_OW + 128 * 64;  // branch 1
  float* biasb = ws + OFF_BIAS;
  int l0 = blockIdx.x * 4;
  for (int it = tid; it < 4 * DIc; it += 256) {
    int d = it & (DIc - 1), pp = it >> 7;
    int l = l0 + pp;
    int www = l % 48, hh = l / 48;
    int lr = l, lcx = www * 48 + hh;
    float v = yb[(0 * Lc + lr) * DIc + d] + yb[(1 * Lc + lcx) * DIc + d] +
              yb[(2 * Lc + (Lc - 1 - lr)) * DIc + d] +
              yb[(3 * Lc + (Lc - 1 - lcx)) * DIc + d];
    yy[pp][d] = v;
  }
  __syncthreads();
  {
    int wv = tid >> 6, c = tid & 63;
    float a = yy[wv][c], b = yy[wv][c + 64];
    float s1 = wsum(a + b);
    float s2 = wsum(a * a + b * b);
    float mu = s1 * (1.f / 128.f);
    float var = s2 * (1.f / 128.f) - mu * mu;
    if (c == 0) { mnv[wv] = mu; isv[wv] = rsqrtf(var + 1e-6f); }
  }
  __syncthreads();
  for (int it = tid; it < 4 * DIc; it += 256) {
    int d = it & (DIc - 1), pp = it >> 7;
    int l = l0 + pp;
    float m = (yy[pp][d] - mnv[pp]) * isv[pp] * p.onw[DIc + d] + p.onb[DIc + d];
    float zv = zb[l * DIc + d];
    ml[pp][d] = m * zv * sigmoidf(zv);
  }
  __syncthreads();
  {
    int pp = tid >> 6, c = tid & 63;
    int l = l0 + pp;
    float acc = p.ob[Cc + c];
    for (int d2 = 0; d2 < DIc; d2++) acc += owT[d2 * 64 + c] * ml[pp][d2];
    biasb[(slot * Lc + l) * Cc + c] = acc;
  }
}

// ---------------------------------------------------------------------------
// s-branch epilogue (slot 4, branch 0): combine + LN + silu(z) + out-proj,
// state update; if fuse: KL + in-proj for next round; if finalw: write d_out.
__global__ __launch_bounds__(256) void g_out_s(Params p, int targ, int fuse, int finalw,
                                               const float* curb, float* nxtb) {
  __shared__ float yy[4][DIc];
  __shared__ float ml[4][DIc];
  __shared__ float xvs[4][64];
  __shared__ float mnv[4], isv[4];
  int tid = threadIdx.x;
  float* ws = p.ws;
  float* base = ws + (size_t)4 * SLOTF;
  const float* yb = base + OFF_Y;
  const float* zb = base + OFF_Z;
  float* xcpre = base + OFF_XCPRE;
  float* zbuf  = base + OFF_Z;
  const float* owT  = ws + OFF_TW + TW_OW;    // branch 0
  const float* inwT = ws + OFF_TW + TW_INW;   // branch 0
  const float* biasb = ws + OFF_BIAS;
  int l0 = blockIdx.x * 4;
  for (int it = tid; it < 4 * DIc; it += 256) {
    int d = it & (DIc - 1), pp = it >> 7;
    int l = l0 + pp;
    int www = l % 48, hh = l / 48;
    int lr = l, lcx = www * 48 + hh;
    float v = yb[(0 * Lc + lr) * DIc + d] + yb[(1 * Lc + lcx) * DIc + d] +
              yb[(2 * Lc + (Lc - 1 - lr)) * DIc + d] +
              yb[(3 * Lc + (Lc - 1 - lcx)) * DIc + d];
    yy[pp][d] = v;
  }
  __syncthreads();
  {
    int wv = tid >> 6, c = tid & 63;
    float a = yy[wv][c], b = yy[wv][c + 64];
    float s1 = wsum(a + b);
    float s2 = wsum(a * a + b * b);
    float mu = s1 * (1.f / 128.f);
    float var = s2 * (1.f / 128.f) - mu * mu;
    if (c == 0) { mnv[wv] = mu; isv[wv] = rsqrtf(var + 1e-6f); }
  }
  __syncthreads();
  for (int it = tid; it < 4 * DIc; it += 256) {
    int d = it & (DIc - 1), pp = it >> 7;
    int l = l0 + pp;
    float m = (yy[pp][d] - mnv[pp]) * isv[pp] * p.onw[d] + p.onb[d];
    float zv = zb[l * DIc + d];
    ml[pp][d] = m * zv * sigmoidf(zv);
  }
  __syncthreads();
  {
    int pp = tid >> 6, c = tid & 63;
    int l = l0 + pp;
    float acc = p.ob[c];
    for (int d2 = 0; d2 < DIc; d2++) acc += owT[d2 * 64 + c] * ml[pp][d2];
    float cv = curb[l * Cc + c];
    float nv = cv * __expf(acc) + biasb[(targ * Lc + l) * Cc + c];
    nxtb[l * Cc + c] = nv;
    if (finalw) p.outp[c * Lc + l] = nv;
    if (fuse) {
      float mp = wmax(cv);
      float sp = wsum(__expf(cv - mp));
      float lp = cv - mp - __logf(sp);
      float mq = wmax(nv);
      float sq = wsum(__expf(nv - mq));
      float lq = nv - mq - __logf(sq);
      xvs[pp][c] = __expf(lp) * (lp - lq);
    }
  }
  if (fuse) {
    __syncthreads();
    int d = tid;
    float acc[4] = {0.f, 0.f, 0.f, 0.f};
    for (int cc = 0; cc < Cc; cc++) {
      float wval = inwT[cc * 256 + d];
#pragma unroll
      for (int pp = 0; pp < 4; pp++) acc[pp] += wval * xvs[pp][cc];
    }
    float bv = p.in_b[d];
    if (d < DIc) {
#pragma unroll
      for (int pp = 0; pp < 4; pp++) xcpre[(l0 + pp) * DIc + d] = acc[pp] + bv;
    } else {
      int dd = d - DIc;
#pragma unroll
      for (int pp = 0; pp < 4; pp++) zbuf[(l0 + pp) * DIc + dd] = acc[pp] + bv;
    }
  }
}

// ---------------------------------------------------------------------------
extern "C" void kernel_launch(void* const* d_in, const int* in_sizes, int n_in,
                              void* d_out, int out_size, void* d_ws, size_t ws_size,
                              hipStream_t stream) {
  (void)in_sizes; (void)n_in; (void)out_size; (void)ws_size;
  Params p;
  p.img    = (const float*)d_in[0];
  p.dz     = (const float*)d_in[1];
  p.sigma  = (const float*)d_in[2];
  p.in_w   = (const float*)d_in[3];
  p.in_b   = (const float*)d_in[4];
  p.conv_w = (const float*)d_in[5];
  p.conv_b = (const float*)d_in[6];
  p.xp_w   = (const float*)d_in[7];
  p.dt_w   = (const float*)d_in[8];
  p.dt_b   = (const float*)d_in[9];
  p.A_logs = (const float*)d_in[10];
  p.Ds     = (const float*)d_in[11];
  p.onw    = (const float*)d_in[12];
  p.onb    = (const float*)d_in[13];
  p.ow     = (const float*)d_in[14];
  p.ob     = (const float*)d_in[15];
  p.niw    = (const float*)d_in[16];
  p.nib    = (const float*)d_in[17];
  p.ndw    = (const float*)d_in[18];
  p.ndb    = (const float*)d_in[19];
  p.outp   = (float*)d_out;
  p.ws     = (float*)d_ws;

  // NOTE: cooperative mega-kernel removed — measured 3.4x slower (grid.sync
  // forces cross-XCD L2 flushes: 343 MB HBM traffic vs ~150 MB, VALUBusy 7.6%).

  hipLaunchKernelGGL(g_transpose, dim3(144), dim3(256), 0, stream, p);
  // mega round: bias t=0..3 (slots 0-3) + s-branch t=0 (slot 4, prep fused)
  hipLaunchKernelGGL(g_inproj, dim3(288, 5), dim3(256), 0, stream, p);
  hipLaunchKernelGGL(g_conv, dim3(576, 5), dim3(256), 0, stream, p, 0);
  hipLaunchKernelGGL(g_scan1, dim3(288, 5), dim3(256), 0, stream, p, 0);
  hipLaunchKernelGGL(g_mid, dim3(32, 5), dim3(256), 0, stream, p, 0);
  hipLaunchKernelGGL(g_scan2, dim3(288, 5), dim3(256), 0, stream, p, 0);
  hipLaunchKernelGGL(g_out_bias, dim3(576, 4), dim3(256), 0, stream, p);

  float* b1 = p.ws + OFF_B1;
  float* b2 = p.ws + OFF_B2;
  hipLaunchKernelGGL(g_out_s, dim3(576), dim3(256), 0, stream, p, 0, 1, 0,
                     (const float*)b1, b2);
  for (int t = 1; t < Tc; t++) {
    const float* curb = (t & 1) ? b2 : b1;
    float* nxtb       = (t & 1) ? b1 : b2;
    hipLaunchKernelGGL(g_conv, dim3(576, 1), dim3(256), 0, stream, p, 4);
    hipLaunchKernelGGL(g_scan1, dim3(288, 1), dim3(256), 0, stream, p, 4);
    hipLaunchKernelGGL(g_mid, dim3(32, 1), dim3(256), 0, stream, p, 4);
    hipLaunchKernelGGL(g_scan2, dim3(288, 1), dim3(256), 0, stream, p, 4);
    hipLaunchKernelGGL(g_out_s, dim3(576), dim3(256), 0, stream, p,
                       t, (t == Tc - 1) ? 0 : 1, (t == Tc - 1) ? 1 : 0, curb, nxtb);
  }
}